// Round 1
// baseline (888.470 us; speedup 1.0000x reference)
//
#include <hip/hip_runtime.h>
#include <math.h>

// Problem constants (x: [2,16,2048,2048] fp32, W: [2048,2048], b: [2048])
constexpr int S      = 2048;
constexpr int BH     = 32;            // 2*16 heads
constexpr int NROWS  = BH * S;        // 65536 rows of length S
constexpr int KS     = 16;            // split-K factor for the small GEMM
constexpr int KR     = S / KS;        // 128 K per split

// ws layout:
//   [0,                 NROWS*4)        : G    float[NROWS]   row maxes (G[bh*S+s])
//   [NROWS*4,           2*NROWS*4)      : IDX  int[NROWS]     argmax col per row
//   [2*NROWS*4,         +KS*NROWS*4)    : part float[KS][BH][S] split-K partials
// total = 256KB + 256KB + 4MB = 4.5 MB

// ---------------------------------------------------------------------------
// Kernel A: fused copy x->out + per-row (max, argmax). One 64-lane wave per row.
// Row = 2048 floats = 8 float4 per lane. Coalesced 16B/lane loads and stores.
// ---------------------------------------------------------------------------
__global__ __launch_bounds__(256) void rowmax_copy_kernel(
    const float* __restrict__ x, float* __restrict__ out,
    float* __restrict__ G, int* __restrict__ IDX)
{
    const int wave = threadIdx.x >> 6;
    const int lane = threadIdx.x & 63;
    const int row  = blockIdx.x * 4 + wave;

    const float4* xr   = (const float4*)(x   + (size_t)row * S);
    float4*       outr = (float4*)      (out + (size_t)row * S);

    float best = -INFINITY;
    int   bidx = 0;
    #pragma unroll
    for (int c = 0; c < 8; ++c) {
        const int v4 = c * 64 + lane;        // float4 index within row
        float4 v = xr[v4];
        outr[v4] = v;
        const int base = v4 * 4;
        // strict '>' with increasing index order => first occurrence per lane
        if (v.x > best) { best = v.x; bidx = base;     }
        if (v.y > best) { best = v.y; bidx = base + 1; }
        if (v.z > best) { best = v.z; bidx = base + 2; }
        if (v.w > best) { best = v.w; bidx = base + 3; }
    }
    // wave (64-lane) reduction; tie -> smaller index (jnp.argmax first-occurrence)
    #pragma unroll
    for (int off = 32; off > 0; off >>= 1) {
        float ov = __shfl_down(best, off, 64);
        int   oi = __shfl_down(bidx, off, 64);
        if (ov > best || (ov == best && oi < bidx)) { best = ov; bidx = oi; }
    }
    if (lane == 0) {
        G[row]   = best;
        IDX[row] = bidx;
    }
}

// ---------------------------------------------------------------------------
// Kernel B: split-K GEMM  Y[bh][t] = sum_s G[bh][s] * W[t][s]
// Grid (S/256, KS). Each thread owns one t and all 32 bh accumulators.
// G K-tile staged in LDS (all main-loop LDS reads are wave-uniform broadcasts).
// W is read exactly once across the grid (16 MB).
// ---------------------------------------------------------------------------
__global__ __launch_bounds__(256) void gemm_part_kernel(
    const float* __restrict__ G, const float* __restrict__ W,
    float* __restrict__ part)
{
    __shared__ float g_lds[BH * KR];          // 32*128 floats = 16 KB
    const int tid = threadIdx.x;
    const int k0  = blockIdx.y * KR;

    // Stage G[:, k0:k0+KR] -> LDS. 4096 floats / 256 threads = 16 each.
    #pragma unroll
    for (int r = 0; r < (BH * KR) / 256; ++r) {
        const int lid = tid + r * 256;
        const int bh  = lid >> 7;             // /KR (KR==128)
        const int kk  = lid & (KR - 1);
        g_lds[lid] = G[bh * S + k0 + kk];     // coalesced global read
    }
    __syncthreads();

    const int t = blockIdx.x * 256 + tid;
    float acc[BH];
    #pragma unroll
    for (int bh = 0; bh < BH; ++bh) acc[bh] = 0.0f;

    const float4* wr = (const float4*)(W + (size_t)t * S + k0);
    for (int k = 0; k < KR; k += 4) {
        const float4 w = wr[k >> 2];
        #pragma unroll
        for (int bh = 0; bh < BH; ++bh) {
            const float4 g = *(const float4*)&g_lds[bh * KR + k];
            acc[bh] += w.x * g.x + w.y * g.y + w.z * g.z + w.w * g.w;
        }
    }

    #pragma unroll
    for (int bh = 0; bh < BH; ++bh) {
        // part[ks][bh][t] — coalesced (t contiguous across lanes)
        part[(size_t)(blockIdx.y * BH + bh) * S + t] = acc[bh];
    }
}

// ---------------------------------------------------------------------------
// Kernel C: reduce split-K partials + bias, exact-erf GELU, scatter into out.
// ---------------------------------------------------------------------------
__global__ __launch_bounds__(256) void finish_kernel(
    const float* __restrict__ part, const float* __restrict__ bias,
    const int* __restrict__ IDX, float* __restrict__ out)
{
    const int o  = blockIdx.x * 256 + threadIdx.x;  // 0..NROWS-1 == (bh, t)
    const int t  = o & (S - 1);
    const int bh = o >> 11;

    float s = bias[t];
    #pragma unroll
    for (int ks = 0; ks < KS; ++ks)
        s += part[(size_t)(ks * BH + bh) * S + t];

    // exact GELU: 0.5*x*(1+erf(x/sqrt(2)))
    const float y = 0.5f * s * (1.0f + erff(s * 0.70710678118654752440f));

    const int idx = IDX[o];
    out[(size_t)o * S + idx] = y;
}

extern "C" void kernel_launch(void* const* d_in, const int* in_sizes, int n_in,
                              void* d_out, int out_size, void* d_ws, size_t ws_size,
                              hipStream_t stream) {
    const float* x = (const float*)d_in[0];   // [2,16,2048,2048]
    const float* W = (const float*)d_in[1];   // [2048,2048]
    const float* b = (const float*)d_in[2];   // [2048]
    float* out = (float*)d_out;

    float* G    = (float*)d_ws;
    int*   IDX  = (int*)  ((char*)d_ws + (size_t)NROWS * 4);
    float* part = (float*)((char*)d_ws + (size_t)2 * NROWS * 4);

    // A: copy + row max/argmax (memory-bound, ~1 GB HBM traffic)
    rowmax_copy_kernel<<<NROWS / 4, 256, 0, stream>>>(x, out, G, IDX);

    // B: split-K GEMM partials
    dim3 gridB(S / 256, KS);
    gemm_part_kernel<<<gridB, 256, 0, stream>>>(G, W, part);

    // C: reduce + GELU + scatter
    finish_kernel<<<NROWS / 256, 256, 0, stream>>>(part, b, IDX, out);
}